// Round 7
// baseline (209.217 us; speedup 1.0000x reference)
//
#include <hip/hip_runtime.h>
#include <hip/hip_bf16.h>

// Problem: N=8192 tokens, K=4096 quant dim, D=1024 out dim.
// out[n, d] = W[d, argmax_k x[n, k]]   (first-occurrence tie-break)
//
// R1: W column gather amplified HBM fetch 16x -> transpose W into d_ws (R2).
// R4: ILP + nontemporal streams (-6us). R5: wave-per-row: neutral (BW-bound).
// R6: cooperative grid.sync() silently failed to launch -> abandoned.
// R7: kernel1 = W-tile transpose (independent job) + argmax(8 rows) fused in
//     one dispatch (transpose traffic hides under the x stream); kernel2 =
//     pure row-copy gather out[n,:] = Wt[k[n],:]. Two launches, no grid sync.

constexpr int N = 8192;
constexpr int K = 4096;
constexpr int D = 1024;

typedef float vf4 __attribute__((ext_vector_type(4))); // clang-native float4

__device__ __forceinline__ int argmax_row(const float* __restrict__ x,
                                          int n, int lane)
{
    const vf4* xv = (const vf4*)(x + (size_t)n * K);
    vf4 v[16];
    #pragma unroll
    for (int j = 0; j < 16; ++j)
        v[j] = __builtin_nontemporal_load(&xv[j * 64 + lane]);

    float best = -__builtin_inff();
    int bidx = 0;
    // Element index (j*64+lane)*4+c increases with j,c within a lane:
    // strict '>' keeps the first occurrence.
    #pragma unroll
    for (int j = 0; j < 16; ++j) {
        const int base = (j * 64 + lane) * 4;
        if (v[j].x > best) { best = v[j].x; bidx = base + 0; }
        if (v[j].y > best) { best = v[j].y; bidx = base + 1; }
        if (v[j].z > best) { best = v[j].z; bidx = base + 2; }
        if (v[j].w > best) { best = v[j].w; bidx = base + 3; }
    }
    #pragma unroll
    for (int off = 32; off > 0; off >>= 1) {
        const float ov = __shfl_down(best, off, 64);
        const int   oi = __shfl_down(bidx, off, 64);
        if (ov > best || (ov == best && oi < bidx)) { best = ov; bidx = oi; }
    }
    return __shfl(bidx, 0, 64);
}

// ---- Kernel 1: 1024 blocks. Each block: (a) transpose one 64x64 W tile
// ---- into Wt, (b) argmax for 8 rows (2 per wave), write k to idx[].
__global__ __launch_bounds__(256) void steq_transpose_argmax(
    const float* __restrict__ x,
    const float* __restrict__ W,
    float* __restrict__ Wt,
    int* __restrict__ idx)
{
    const int t = threadIdx.x;
    const int lane = t & 63;
    const int wave = t >> 6;
    const int b = blockIdx.x; // 0..1023

    // (a) transpose tile: k-tile = b&63, d-tile = b>>6
    {
        __shared__ float tile[64][65];
        const int k0 = (b & 63) * 64;
        const int d0 = (b >> 6) * 64;
        const int tx = t % 16, ty = t / 16;
        #pragma unroll
        for (int p = 0; p < 4; ++p) {
            const int r = p * 16 + ty; // d_local
            const vf4 v = *(const vf4*)(W + (size_t)(d0 + r) * K + k0 + tx * 4);
            tile[r][tx * 4 + 0] = v.x;
            tile[r][tx * 4 + 1] = v.y;
            tile[r][tx * 4 + 2] = v.z;
            tile[r][tx * 4 + 3] = v.w;
        }
        __syncthreads();
        #pragma unroll
        for (int p = 0; p < 4; ++p) {
            const int r = p * 16 + ty; // k_local
            vf4 o;
            o.x = tile[tx * 4 + 0][r];
            o.y = tile[tx * 4 + 1][r];
            o.z = tile[tx * 4 + 2][r];
            o.w = tile[tx * 4 + 3][r];
            *(vf4*)(Wt + (size_t)(k0 + r) * D + d0 + tx * 4) = o;
        }
    }

    // (b) argmax for rows b*8 + wave*2 + {0,1}
    const int n0 = b * 8 + wave * 2;
    const int ka = argmax_row(x, n0 + 0, lane);
    const int kb = argmax_row(x, n0 + 1, lane);
    if (lane == 0) {
        idx[n0 + 0] = ka;
        idx[n0 + 1] = kb;
    }
}

// ---- Kernel 2: pure gather row-copy. Wave per row, 2048 blocks x 256. ----
__global__ __launch_bounds__(256) void steq_gather(
    const float* __restrict__ Wt,
    const int* __restrict__ idx,
    float* __restrict__ out)
{
    const int t = threadIdx.x;
    const int lane = t & 63;
    const int wave = t >> 6;
    const int n = blockIdx.x * 4 + wave;

    const int k = idx[n]; // wave-uniform scalar load
    const vf4* wrow = (const vf4*)(Wt + (size_t)k * D);
    vf4* orow = (vf4*)(out + (size_t)n * D);
    vf4 g[4];
    #pragma unroll
    for (int j = 0; j < 4; ++j) g[j] = wrow[j * 64 + lane];
    #pragma unroll
    for (int j = 0; j < 4; ++j)
        __builtin_nontemporal_store(g[j], &orow[j * 64 + lane]);
}

extern "C" void kernel_launch(void* const* d_in, const int* in_sizes, int n_in,
                              void* d_out, int out_size, void* d_ws, size_t ws_size,
                              hipStream_t stream) {
    const float* x = (const float*)d_in[0];
    const float* W = (const float*)d_in[1];
    float* out = (float*)d_out;
    float* Wt  = (float*)d_ws;                        // 16 MiB
    int*   idx = (int*)((char*)d_ws + (size_t)K * D * 4); // 32 KiB after Wt

    steq_transpose_argmax<<<1024, 256, 0, stream>>>(x, W, Wt, idx);
    steq_gather<<<N / 4, 256, 0, stream>>>(Wt, idx, out);
}